// Round 7
// baseline (395.548 us; speedup 1.0000x reference)
//
#include <hip/hip_runtime.h>

#define T_STEPS 1024
#define CC 6
#define NCHUNK 16                  // time chunks per row (1 thread per chunk)
#define CHUNK (T_STEPS / NCHUNK)   // 64
#define WARM 16                    // warm-up steps per chunk (error ~0.08^15)
#define KBUF 16                    // steps per register-buffered burst
#define NBLK (CHUNK / KBUF)        // 4 bursts per chunk
#define BUFN (KBUF * CC)           // 96 floats = 384 B = 3 x 128-B lines
#define LOG2E 1.4426950408889634f
#define LN2   0.6931471805599453f

__device__ __forceinline__ float fexp2(float x) {
#if __has_builtin(__builtin_amdgcn_exp2f)
    return __builtin_amdgcn_exp2f(x);
#else
    return exp2f(x);
#endif
}

__device__ __forceinline__ float flog2(float x) {
#if __has_builtin(__builtin_amdgcn_logf)
    return __builtin_amdgcn_logf(x);   // v_log_f32 = log2
#else
    return log2f(x);
#endif
}

// One THREAD per (row, time-chunk) chain. State (6 floats) and the 6x6
// row-softmax matrix (36 floats) live in registers; the step is pure register
// math (36 mul + 36 exp2 + 30 add + 6 log2 + 12 fma) with 36-wide ILP and NO
// cross-lane dependency (rounds 3-5: the 8-lane layout paid a ~120-cyc LDS
// round-trip inside the serial chain every step for zero compute savings).
//
// Round-6 bug fixed here: the burst flush must write BUFN/4 = 24 float4s
// (96 dwords), not 6 -- round 6 silently dropped 12 of every 16 steps.
//
// IO: one 96-float register buffer per burst, loaded with 24 dwordx4
// (16 steps of x), updated in place (step kk reads buf[kk*6..], overwrites
// with new state; fully unrolled -> static indices), flushed with 24 dwordx4
// = exactly 3 aligned 128-B lines per thread (no partial-line amplification).
//
// Chunks c>0 warm up WARM=16 steps seeded with state = x at t0-WARM:
// per-step contraction (1-a)*max(Tn) ~ 0.08 -> seed error < 1e-16.
__global__ __launch_bounds__(256, 1) void transfer_kernel(
    const float* __restrict__ feats,
    const float* __restrict__ alpha,
    const float* __restrict__ trans,
    float* __restrict__ out, int B)
{
    int tid = blockIdx.x * blockDim.x + threadIdx.x;
    if (tid >= B * NCHUNK) return;
    int b = tid % B;   // consecutive threads -> consecutive rows
    int c = tid / B;   // wave-uniform chunk index (B % 64 == 0)

    // a = sigmoid(alpha)
    float a  = 1.0f / (1.0f + fexp2(-alpha[0] * LOG2E));
    float c1 = (1.0f - a) * LN2;   // (1-a)*ln2: log2-sum -> natural te

    // full row-softmax(trans), pre-scaled by log2e: tm[i][j] = Tn[i][j]*LOG2E
    float tm[CC][CC];
#pragma unroll
    for (int i = 0; i < CC; ++i) {
        float rs = 0.0f;
#pragma unroll
        for (int k = 0; k < CC; ++k)
            rs += fexp2(trans[i * CC + k] * LOG2E);
        float inv = LOG2E / rs;
#pragma unroll
        for (int jj = 0; jj < CC; ++jj)
            tm[i][jj] = fexp2(trans[i * CC + jj] * LOG2E) * inv;
    }

    const float* fb = feats + (size_t)b * T_STEPS * CC;
    float*       ob = out   + (size_t)b * T_STEPS * CC;

    float st[CC];
    float buf[BUFN];   // statically indexed everywhere after unroll

    // load 16 steps of x starting at T0 (byte base 24*T0: 128-aligned for all
    // uses here since T0 is a multiple of 16)
#define LOADBURST(T0)                                                        \
    do {                                                                     \
        _Pragma("unroll")                                                    \
        for (int k = 0; k < BUFN / 4; ++k) {                                 \
            float4 v = *reinterpret_cast<const float4*>(&fb[(T0) * CC + 4 * k]); \
            buf[4 * k + 0] = v.x; buf[4 * k + 1] = v.y;                      \
            buf[4 * k + 2] = v.z; buf[4 * k + 3] = v.w;                      \
        }                                                                    \
    } while (0)

    // advance one step using x = buf[KK*6..], write new state back in place
#define STEPB(KK)                                                         \
    do {                                                                  \
        float ns[CC];                                                     \
        _Pragma("unroll")                                                 \
        for (int jj = 0; jj < CC; ++jj) {                                 \
            float sum;                                                    \
            sum  = fexp2(st[0] * tm[0][jj]);                              \
            sum += fexp2(st[1] * tm[1][jj]);                              \
            sum += fexp2(st[2] * tm[2][jj]);                              \
            sum += fexp2(st[3] * tm[3][jj]);                              \
            sum += fexp2(st[4] * tm[4][jj]);                              \
            sum += fexp2(st[5] * tm[5][jj]);                              \
            ns[jj] = a * buf[(KK) * CC + jj] + c1 * flog2(sum);           \
        }                                                                 \
        _Pragma("unroll")                                                 \
        for (int jj = 0; jj < CC; ++jj) {                                 \
            st[jj] = ns[jj];                                              \
            buf[(KK) * CC + jj] = ns[jj];                                 \
        }                                                                 \
    } while (0)

    int t0 = c * CHUNK;

    if (c != 0) {
        // speculative warm-up: one burst load at t0-WARM (>= 48, in-bounds),
        // seed with x(tw), run WARM-1 steps (writeback is harmless scratch)
        LOADBURST(t0 - WARM);
#pragma unroll
        for (int jj = 0; jj < CC; ++jj) st[jj] = buf[jj];
#pragma unroll
        for (int w = 1; w < WARM; ++w) STEPB(w);
    }
    // (c == 0: state initialized from t = 0 inside the first burst)

#pragma unroll 1
    for (int kb = 0; kb < NBLK; ++kb) {
        int tbase = t0 + kb * KBUF;
        LOADBURST(tbase);

        if (kb == 0 && c == 0) {        // wave-uniform branch
#pragma unroll
            for (int jj = 0; jj < CC; ++jj) st[jj] = buf[jj];  // t=0: emit as-is
#pragma unroll
            for (int kk = 1; kk < KBUF; ++kk) STEPB(kk);
        } else {
#pragma unroll
            for (int kk = 0; kk < KBUF; ++kk) STEPB(kk);
        }

        // flush: 24 dwordx4 = full 96 dwords = 3 aligned 128-B lines
#pragma unroll
        for (int k = 0; k < BUFN / 4; ++k) {
            float4 v = make_float4(buf[4 * k + 0], buf[4 * k + 1],
                                   buf[4 * k + 2], buf[4 * k + 3]);
            *reinterpret_cast<float4*>(&ob[tbase * CC + 4 * k]) = v;
        }
    }
#undef STEPB
#undef LOADBURST
}

extern "C" void kernel_launch(void* const* d_in, const int* in_sizes, int n_in,
                              void* d_out, int out_size, void* d_ws, size_t ws_size,
                              hipStream_t stream) {
    const float* feats = (const float*)d_in[0];
    const float* alpha = (const float*)d_in[1];
    const float* trans = (const float*)d_in[2];
    float* out = (float*)d_out;

    int B = in_sizes[0] / (T_STEPS * CC);   // 8192 (same convention as verified rounds)

    int threads = B * NCHUNK;               // 1 thread per (row, chunk)
    int block   = 256;
    int grid    = (threads + block - 1) / block;

    hipLaunchKernelGGL(transfer_kernel, dim3(grid), dim3(block), 0, stream,
                       feats, alpha, trans, out, B);
}